// Round 1
// baseline (583.796 us; speedup 1.0000x reference)
//
#include <hip/hip_runtime.h>
#include <stdint.h>

// Problem constants
#define B_ 4
#define S_ 2048
#define D_ 1024
#define H_ 16
#define DK_ 64
#define M_ (B_*S_)   // 8192 rows

typedef __attribute__((ext_vector_type(8))) short bhalf8;   // 8 x bf16 (4 VGPRs)
typedef __attribute__((ext_vector_type(4))) float floatx4;  // MFMA accumulator
typedef unsigned short bfu;
typedef unsigned int u32;

// fp32 -> bf16 (RNE), branchless
__device__ __forceinline__ bfu f2bf(float f) {
  union { float f; u32 u; } v; v.f = f;
  u32 r = v.u + 0x7FFFu + ((v.u >> 16) & 1u);
  return (bfu)(r >> 16);
}

// ---------------- conversion kernel ----------------
__global__ void cvt_f32_bf16(const float* __restrict__ src, bfu* __restrict__ dst, int n) {
  int i = (blockIdx.x * blockDim.x + threadIdx.x) * 4;
  if (i >= n) return;
  float4 v = *(const float4*)(src + i);
  ushort4 o;
  o.x = f2bf(v.x); o.y = f2bf(v.y); o.z = f2bf(v.z); o.w = f2bf(v.w);
  *(ushort4*)(dst + i) = o;
}

// ---------------- GEMM core: C[128x128] = A[M,K] * B[N,K]^T (both K-contig bf16) ----------------
// 256 threads = 4 waves (2x2), each wave owns 64x64 = 4x4 MFMA frags of 16x16.
// BK=64. LDS tiles [128][64] bf16, XOR-swizzled (byte ^= (row&7)<<4) so both
// ds_write_b128 (stage) and ds_read_b128 (frags) are <=2-way per 16-lane phase.
__device__ __forceinline__ void gemm_core(const bfu* __restrict__ A,
                                          const bfu* __restrict__ Bw,
                                          bfu* aT, bfu* bT,
                                          int m0, int n0,
                                          floatx4 (&acc)[4][4])
{
  const int tid  = threadIdx.x;
  const int lane = tid & 63;
  const int g    = lane >> 4;     // 0..3  (k-subgroup)
  const int i16  = lane & 15;     // row/col within 16
  const int w    = tid >> 6;
  const int wm   = w >> 1, wn = w & 1;

  for (int k0 = 0; k0 < D_; k0 += 64) {
    // global -> regs (issued before the barrier: overlaps prior compute)
    bhalf8 ra[4], rb[4];
#pragma unroll
    for (int l = 0; l < 4; ++l) {
      int e = (l * 256 + tid) * 8;          // element within 128x64 tile
      int row = e >> 6, col = e & 63;
      ra[l] = *(const bhalf8*)(A  + (size_t)(m0 + row) * D_ + k0 + col);
      rb[l] = *(const bhalf8*)(Bw + (size_t)(n0 + row) * D_ + k0 + col);
    }
    __syncthreads();   // previous iter's LDS reads complete
#pragma unroll
    for (int l = 0; l < 4; ++l) {
      int e = (l * 256 + tid) * 8;
      int row = e >> 6, colb = (e & 63) * 2;
      int sw = colb ^ ((row & 7) << 4);
      *(bhalf8*)((char*)aT + row * 128 + sw) = ra[l];
      *(bhalf8*)((char*)bT + row * 128 + sw) = rb[l];
    }
    __syncthreads();   // tile staged
#pragma unroll
    for (int kb = 0; kb < 2; ++kb) {
      bhalf8 af[4], bf[4];
#pragma unroll
      for (int f = 0; f < 4; ++f) {
        int arow = wm * 64 + f * 16 + i16;
        af[f] = *(const bhalf8*)((const char*)aT + arow * 128 + ((kb * 64 + g * 16) ^ ((arow & 7) << 4)));
        int brow = wn * 64 + f * 16 + i16;
        bf[f] = *(const bhalf8*)((const char*)bT + brow * 128 + ((kb * 64 + g * 16) ^ ((brow & 7) << 4)));
      }
#pragma unroll
      for (int fm = 0; fm < 4; ++fm)
#pragma unroll
        for (int fn = 0; fn < 4; ++fn)
          acc[fm][fn] = __builtin_amdgcn_mfma_f32_16x16x32_bf16(af[fm], bf[fn], acc[fm][fn], 0, 0, 0);
    }
  }
}

// ---------------- QKV projection GEMM ----------------
// z=0: Q -> [bh][s][dk]; z=1: K -> [bh][s][dk]; z=2: V -> transposed [bh][dk][s]
__global__ __launch_bounds__(256) void proj_gemm(const bfu* __restrict__ xb,
                                                 const bfu* __restrict__ wqb,
                                                 const bfu* __restrict__ wkb,
                                                 const bfu* __restrict__ wvb,
                                                 bfu* __restrict__ Qd,
                                                 bfu* __restrict__ Kd,
                                                 bfu* __restrict__ Vtd)
{
  __shared__ bfu aT[128 * 64], bT[128 * 64];
  const int z = blockIdx.z;
  const bfu* Bw = (z == 0) ? wqb : (z == 1) ? wkb : wvb;
  bfu* dst      = (z == 0) ? Qd  : (z == 1) ? Kd  : Vtd;

  floatx4 acc[4][4] = {};
  const int m0 = blockIdx.y * 128, n0 = blockIdx.x * 128;
  gemm_core(xb, Bw, aT, bT, m0, n0, acc);

  const int lane = threadIdx.x & 63;
  const int g = lane >> 4, i16 = lane & 15;
  const int w = threadIdx.x >> 6, wm = w >> 1, wn = w & 1;
#pragma unroll
  for (int fm = 0; fm < 4; ++fm) {
#pragma unroll
    for (int fn = 0; fn < 4; ++fn) {
      int col = n0 + wn * 64 + fn * 16 + i16;
      int h = col >> 6, dk = col & 63;
#pragma unroll
      for (int r = 0; r < 4; ++r) {
        int mrow = m0 + wm * 64 + fm * 16 + g * 4 + r;
        int b = mrow >> 11, s = mrow & (S_ - 1);
        size_t idx = (z == 2)
            ? ((size_t)((b * H_ + h) * DK_ + dk)) * S_ + s    // V^T
            : ((size_t)((b * H_ + h) * S_ + s)) * DK_ + dk;   // Q,K
        dst[idx] = f2bf(acc[fm][fn][r]);
      }
    }
  }
}

// ---------------- flash attention (causal) ----------------
// grid (S/64, B*H), 256 thr = 4 independent waves; wave w owns q rows [q0+16w, q0+16w+16)
__global__ __launch_bounds__(256) void attn_kernel(const bfu* __restrict__ Q,
                                                   const bfu* __restrict__ Kc,
                                                   const bfu* __restrict__ Vt,
                                                   bfu* __restrict__ Oc)
{
  __shared__ char plds[4 * 2048];   // per-wave 16x64 bf16 P tile, XOR-swizzled
  const int tid = threadIdx.x;
  const int lane = tid & 63;
  const int w = tid >> 6;
  const int g = lane >> 4, i16 = lane & 15;
  const int bh = blockIdx.y;
  const int q0 = blockIdx.x * 64;
  const int qr = q0 + w * 16;
  char* pw = plds + w * 2048;

  const bfu* Qb = Q  + (size_t)bh * S_ * DK_;
  const bfu* Kb = Kc + (size_t)bh * S_ * DK_;
  const bfu* Vb = Vt + (size_t)bh * DK_ * S_;

  // Q frags hoisted (rows = wave's 16 q rows, k = dk)
  bhalf8 qa[2];
#pragma unroll
  for (int kb = 0; kb < 2; ++kb)
    qa[kb] = *(const bhalf8*)(Qb + (size_t)(qr + i16) * DK_ + kb * 32 + g * 8);

  floatx4 o[4] = {};
  float m[4], l[4];
#pragma unroll
  for (int r = 0; r < 4; ++r) { m[r] = -3.0e38f; l[r] = 0.f; }

  const int ntiles = blockIdx.x + 1;   // causal: kv tiles 0..q-tile index
  for (int t = 0; t < ntiles; ++t) {
    const int kv0 = t * 64;
    // ---- S = Q K^T (scaled later) ----
    floatx4 sa[4] = {};
#pragma unroll
    for (int cb = 0; cb < 4; ++cb) {
#pragma unroll
      for (int kb = 0; kb < 2; ++kb) {
        bhalf8 kf = *(const bhalf8*)(Kb + (size_t)(kv0 + cb * 16 + i16) * DK_ + kb * 32 + g * 8);
        sa[cb] = __builtin_amdgcn_mfma_f32_16x16x32_bf16(qa[kb], kf, sa[cb], 0, 0, 0);
      }
    }
    // ---- scale + causal mask + row max ----
    const bool lastt = (t == ntiles - 1);
    float pm[4];
#pragma unroll
    for (int r = 0; r < 4; ++r) pm[r] = -3.0e38f;
#pragma unroll
    for (int cb = 0; cb < 4; ++cb) {
      int col = kv0 + cb * 16 + i16;
#pragma unroll
      for (int r = 0; r < 4; ++r) {
        float v = sa[cb][r] * 0.125f;              // DK^-0.5
        if (lastt && col > qr + g * 4 + r) v = -3.0e38f;
        sa[cb][r] = v;
        pm[r] = fmaxf(pm[r], v);
      }
    }
#pragma unroll
    for (int r = 0; r < 4; ++r) {
      float v = pm[r];
      v = fmaxf(v, __shfl_xor(v, 1));
      v = fmaxf(v, __shfl_xor(v, 2));
      v = fmaxf(v, __shfl_xor(v, 4));
      v = fmaxf(v, __shfl_xor(v, 8));
      pm[r] = v;   // row max across 16 cols-lanes (rows live in same 16-lane group)
    }
    float al[4], rs[4];
#pragma unroll
    for (int r = 0; r < 4; ++r) {
      float mn = fmaxf(m[r], pm[r]);
      al[r] = exp2f((m[r] - mn) * 1.44269504f);
      m[r] = mn;
      rs[r] = 0.f;
    }
    // ---- P = exp(S - m), write to per-wave LDS (C-layout -> A-frag via swizzled tile) ----
#pragma unroll
    for (int cb = 0; cb < 4; ++cb) {
#pragma unroll
      for (int r = 0; r < 4; ++r) {
        float p = exp2f((sa[cb][r] - m[r]) * 1.44269504f);
        rs[r] += p;
        int row = g * 4 + r;
        int colb = (cb * 16 + i16) * 2;
        *(bfu*)(pw + row * 128 + (colb ^ ((row & 7) << 4))) = f2bf(p);
      }
    }
#pragma unroll
    for (int r = 0; r < 4; ++r) {
      float v = rs[r];
      v += __shfl_xor(v, 1); v += __shfl_xor(v, 2);
      v += __shfl_xor(v, 4); v += __shfl_xor(v, 8);
      l[r] = l[r] * al[r] + v;
    }
#pragma unroll
    for (int db = 0; db < 4; ++db)
#pragma unroll
      for (int r = 0; r < 4; ++r)
        o[db][r] *= al[r];
    // ---- read P as A-frags ----
    bhalf8 pa[2];
#pragma unroll
    for (int kb = 0; kb < 2; ++kb)
      pa[kb] = *(const bhalf8*)(pw + i16 * 128 + ((kb * 64 + g * 16) ^ ((i16 & 7) << 4)));
    // ---- O += P @ V (V^T global: [dk][s], contiguous in s) ----
#pragma unroll
    for (int db = 0; db < 4; ++db) {
#pragma unroll
      for (int kb = 0; kb < 2; ++kb) {
        bhalf8 vf = *(const bhalf8*)(Vb + (size_t)(db * 16 + i16) * S_ + kv0 + kb * 32 + g * 8);
        o[db] = __builtin_amdgcn_mfma_f32_16x16x32_bf16(pa[kb], vf, o[db], 0, 0, 0);
      }
    }
  }
  // ---- epilogue: O/l -> attn buffer [b][s][h*64+dk] bf16 ----
  const int b = bh >> 4, h = bh & 15;
#pragma unroll
  for (int db = 0; db < 4; ++db) {
#pragma unroll
    for (int r = 0; r < 4; ++r) {
      float v = o[db][r] / l[r];
      int srow = qr + g * 4 + r;
      int col = h * 64 + db * 16 + i16;
      Oc[(size_t)(b * S_ + srow) * D_ + col] = f2bf(v);
    }
  }
}

// ---------------- output projection GEMM (fp32 out) ----------------
__global__ __launch_bounds__(256) void out_gemm(const bfu* __restrict__ Ab,
                                                const bfu* __restrict__ wob,
                                                float* __restrict__ out)
{
  __shared__ bfu aT[128 * 64], bT[128 * 64];
  floatx4 acc[4][4] = {};
  const int m0 = blockIdx.y * 128, n0 = blockIdx.x * 128;
  gemm_core(Ab, wob, aT, bT, m0, n0, acc);

  const int lane = threadIdx.x & 63;
  const int g = lane >> 4, i16 = lane & 15;
  const int w = threadIdx.x >> 6, wm = w >> 1, wn = w & 1;
#pragma unroll
  for (int fm = 0; fm < 4; ++fm)
#pragma unroll
    for (int fn = 0; fn < 4; ++fn) {
      int col = n0 + wn * 64 + fn * 16 + i16;
#pragma unroll
      for (int r = 0; r < 4; ++r) {
        int mrow = m0 + wm * 64 + fm * 16 + g * 4 + r;
        out[(size_t)mrow * D_ + col] = acc[fm][fn][r];
      }
    }
}

// ---------------- launch ----------------
extern "C" void kernel_launch(void* const* d_in, const int* in_sizes, int n_in,
                              void* d_out, int out_size, void* d_ws, size_t ws_size,
                              hipStream_t stream)
{
  const float* x  = (const float*)d_in[0];
  const float* wq = (const float*)d_in[1];
  const float* wk = (const float*)d_in[2];
  const float* wv = (const float*)d_in[3];
  const float* wo = (const float*)d_in[4];

  bfu* xb  = (bfu*)d_ws;                          // [8192][1024]
  bfu* wqb = xb  + (size_t)M_ * D_;
  bfu* wkb = wqb + (size_t)D_ * D_;
  bfu* wvb = wkb + (size_t)D_ * D_;
  bfu* wob = wvb + (size_t)D_ * D_;
  bfu* Qd  = wob + (size_t)D_ * D_;               // [bh][s][dk]
  bfu* Kd  = Qd  + (size_t)M_ * D_;               // [bh][s][dk]
  bfu* Vtd = Kd  + (size_t)M_ * D_;               // [bh][dk][s]
  bfu* Ad  = Vtd + (size_t)M_ * D_;               // attn out bf16 [b][s][d]

  const int thr = 256;
  cvt_f32_bf16<<<(M_ * D_ / 4 + thr - 1) / thr, thr, 0, stream>>>(x, xb, M_ * D_);
  cvt_f32_bf16<<<(D_ * D_ / 4 + thr - 1) / thr, thr, 0, stream>>>(wq, wqb, D_ * D_);
  cvt_f32_bf16<<<(D_ * D_ / 4 + thr - 1) / thr, thr, 0, stream>>>(wk, wkb, D_ * D_);
  cvt_f32_bf16<<<(D_ * D_ / 4 + thr - 1) / thr, thr, 0, stream>>>(wv, wvb, D_ * D_);
  cvt_f32_bf16<<<(D_ * D_ / 4 + thr - 1) / thr, thr, 0, stream>>>(wo, wob, D_ * D_);

  proj_gemm<<<dim3(8, 64, 3), 256, 0, stream>>>(xb, wqb, wkb, wvb, Qd, Kd, Vtd);
  attn_kernel<<<dim3(S_ / 64, B_ * H_), 256, 0, stream>>>(Qd, Kd, Vtd, Ad);
  out_gemm<<<dim3(8, 64), 256, 0, stream>>>(Ad, wob, (float*)d_out);
}